// Round 12
// baseline (137.373 us; speedup 1.0000x reference)
//
#include <hip/hip_runtime.h>
#include <hip/hip_bf16.h>
#include <stdint.h>

#define N 8192
#define FIN 128
#define H 64
#define QB2 64                   // query rows per block (2x16 per wave)
#define MB2 64                   // keys per iteration
#define KSPLIT 4
#define KLEN (N / KSPLIT)        // 2048 keys per block
#define NIT3 (KLEN / MB2)        // 32 iterations
#define STAGE_BYTES 16384        // K 8KB + V^T 8KB

typedef __attribute__((ext_vector_type(4))) short s16x4;
typedef __attribute__((ext_vector_type(8))) short short8;
typedef __attribute__((ext_vector_type(4))) float f32x4;

#define MFMA16(a, b, c) __builtin_amdgcn_mfma_f32_16x16x32_bf16(a, b, c, 0, 0, 0)

typedef __attribute__((address_space(1))) const void* gas_p;
typedef __attribute__((address_space(3))) void* las_p;

static __device__ __forceinline__ void load_lds16(const void* g, void* l) {
    __builtin_amdgcn_global_load_lds((gas_p)g, (las_p)l, 16, 0, 0);
}

static __device__ __forceinline__ unsigned short f2bf(float f) {
    unsigned int u = __float_as_uint(f);
    unsigned int r = (u + 0x7FFFu + ((u >> 16) & 1u)) >> 16;
    return (unsigned short)r;
}

static __device__ __forceinline__ unsigned int cvt_pk_bf16(float a, float b) {
    unsigned int r;
    asm("v_cvt_pk_bf16_f32 %0, %1, %2" : "=v"(r) : "v"(a), "v"(b));
    return r;
}

static __device__ __forceinline__ f32x4 ntl4(const float* p) {
    return __builtin_nontemporal_load((const f32x4*)p);
}

// -------- kernel 0: W -> W^T bf16; W2 pre-scaled by log2(e)/8 (K-side only) --------
__global__ __launch_bounds__(256) void wprep_kernel(const float* __restrict__ W1,
                                                    const float* __restrict__ W2,
                                                    unsigned short* __restrict__ W1T,
                                                    unsigned short* __restrict__ W2T) {
    const int i = blockIdx.x * 256 + threadIdx.x;
    const int h = i >> 7, f = i & 127;
    W1T[i] = f2bf(W1[f * H + h]);
    W2T[i] = f2bf(W2[f * H + h] * 0.18033688011112042f);  // log2(e)/8
}

// -------- kernel 1: MFMA projection + fused Q transpose --------
__global__ __launch_bounds__(256) void proj_kernel(const float* __restrict__ seq,
                                                   const unsigned short* __restrict__ W1T,
                                                   const unsigned short* __restrict__ W2T,
                                                   unsigned short* __restrict__ Qb,
                                                   unsigned short* __restrict__ Kb,
                                                   unsigned short* __restrict__ QT) {
    __shared__ unsigned short t2[64][40];
    const int tid = threadIdx.x;
    const int w = tid >> 6, lane = tid & 63;
    const int g = lane >> 4, c = lane & 15;
    const int wq = w & 1, ww = w >> 1;
    const int r0 = blockIdx.x * 32;
    const int rw = r0 + wq * 16;
    const unsigned short* WT = ww ? W2T : W1T;
    unsigned short* Ob = ww ? Kb : Qb;

    short8 af[4];
#pragma unroll
    for (int kc = 0; kc < 4; ++kc) {
        const float* sp = seq + (size_t)(rw + c) * FIN + kc * 32 + g * 8;
        const f32x4 s0 = *(const f32x4*)sp;
        const f32x4 s1 = *(const f32x4*)(sp + 4);
        short8 v;
#pragma unroll
        for (int j = 0; j < 4; ++j) {
            v[j] = (short)f2bf(s0[j]);
            v[4 + j] = (short)f2bf(s1[j]);
        }
        af[kc] = v;
    }

    f32x4 oa[4] = {};
#pragma unroll
    for (int kc = 0; kc < 4; ++kc) {
#pragma unroll
        for (int ht = 0; ht < 4; ++ht) {
            const short8 wf = *(const short8*)(WT + (size_t)(ht * 16 + c) * FIN + kc * 32 + g * 8);
            oa[ht] = MFMA16(af[kc], wf, oa[ht]);
        }
    }
#pragma unroll
    for (int ht = 0; ht < 4; ++ht)
#pragma unroll
        for (int r = 0; r < 4; ++r) {
            const unsigned short b = f2bf(oa[ht][r]);
            Ob[(size_t)(rw + g * 4 + r) * H + ht * 16 + c] = b;
            if (ww == 0) t2[ht * 16 + c][wq * 16 + g * 4 + r] = b;
        }
    __syncthreads();
    const int h = tid >> 2, part = tid & 3;
    const short8 v = *(const short8*)(&t2[h][part * 8]);
    *(short8*)(QT + (size_t)h * N + r0 + part * 8) = v;
}

// -------- kernel 2: flash partials (template NOBIAS ablation) --------
// NOBIAS=0: the real computation (identical to round 11).
// NOBIAS=1: bias loads+multiply deleted, everything else identical; partials
// go to scratch (pvX/pdX) so the dispatch is live but output-inert.
template <int NOBIAS>
__global__ __launch_bounds__(256) void flash_kernel(const unsigned short* __restrict__ Qb,
                                                    const unsigned short* __restrict__ Kb,
                                                    const unsigned short* __restrict__ QT,
                                                    const float* __restrict__ bias,
                                                    float* __restrict__ pv,
                                                    float* __restrict__ pd) {
    __shared__ char smem[33280];

    const int tid = threadIdx.x;
    const int w = tid >> 6, lane = tid & 63;
    const int g = lane >> 4, c = lane & 15;
    const int wq = w >> 1, wk = w & 1;
    const int bid = blockIdx.x;
    const int q0 = (bid >> 2) * QB2;
    const int mbase = (bid & 3) * KLEN;

    short8 qf[2][2];
#pragma unroll
    for (int qt = 0; qt < 2; ++qt) {
        const unsigned short* qrow = Qb + (size_t)(q0 + wq * 32 + qt * 16 + c) * H + g * 8;
        qf[qt][0] = *(const short8*)(qrow);
        qf[qt][1] = *(const short8*)(qrow + 32);
    }

    f32x4 vals[2][4] = {};
    float dsum[2] = {0.f, 0.f};

    auto stage = [&](char* sbase, int m0) {
#pragma unroll
        for (int s2 = 0; s2 < 2; ++s2) {
            const int s = w * 2 + s2;
            {
                const int m = s * 8 + (lane >> 3);
                const int srcb = ((lane & 7) * 16) ^ ((m & 7) << 4);
                load_lds16((const char*)Kb + (size_t)(mbase + m0 + m) * 128 + srcb,
                           sbase + s * 1024);
            }
            {
                const int h = s * 8 + (lane >> 3);
                const int srcb = ((lane & 7) * 16) ^ ((h & 7) << 4);
                load_lds16((const char*)QT + (size_t)h * (N * 2) + (size_t)(mbase + m0) * 2 + srcb,
                           sbase + 8192 + s * 1024);
            }
        }
    };

    char* b0 = smem;
    char* b1 = smem + STAGE_BYTES;

    const float* bb0 = bias + (size_t)(q0 + wq * 32 + c) * N + mbase + wk * 32 + g * 4;
    const float* bb1 = bb0 + (size_t)16 * N;

    stage(b0, 0);
    f32x4 bcur[4];
    if (!NOBIAS) {
        bcur[0] = ntl4(bb0);      bcur[1] = ntl4(bb0 + 16);
        bcur[2] = ntl4(bb1);      bcur[3] = ntl4(bb1 + 16);
    }
    __syncthreads();

    for (int it = 0; it < NIT3; ++it) {
        f32x4 bn[4];
        if (!NOBIAS) { bn[0] = bcur[0]; bn[1] = bcur[1]; bn[2] = bcur[2]; bn[3] = bcur[3]; }
        if (it + 1 < NIT3) {
            stage(b1, (it + 1) * MB2);
            if (!NOBIAS) {
                const int o = (it + 1) * MB2;
                bn[0] = ntl4(bb0 + o);      bn[1] = ntl4(bb0 + o + 16);
                bn[2] = ntl4(bb1 + o);      bn[3] = ntl4(bb1 + o + 16);
            }
        }

        const char* kb = b0;
        const char* vb = b0 + 8192;

        short8 kf[2][2];
#pragma unroll
        for (int t = 0; t < 2; ++t) {
            const int m = wk * 32 + t * 16 + c;
            const char* kr = kb + m * 128;
            const int sw = (m & 7) << 4;
            kf[t][0] = *(const short8*)(kr + ((g * 16) ^ sw));
            kf[t][1] = *(const short8*)(kr + ((64 + g * 16) ^ sw));
        }

        union { unsigned u[4]; short8 s; } pau[2];
#pragma unroll
        for (int qt = 0; qt < 2; ++qt) {
            f32x4 acc0 = {}, acc1 = {};
            acc0 = MFMA16(kf[0][0], qf[qt][0], acc0);
            acc0 = MFMA16(kf[0][1], qf[qt][1], acc0);
            acc1 = MFMA16(kf[1][0], qf[qt][0], acc1);
            acc1 = MFMA16(kf[1][1], qf[qt][1], acc1);

            float p00, p01, p02, p03, p10, p11, p12, p13;
            if (!NOBIAS) {
                const f32x4 bc0 = bcur[qt * 2];
                const f32x4 bc1 = bcur[qt * 2 + 1];
                p00 = exp2f(acc0[0]) * bc0[0];
                p01 = exp2f(acc0[1]) * bc0[1];
                p02 = exp2f(acc0[2]) * bc0[2];
                p03 = exp2f(acc0[3]) * bc0[3];
                p10 = exp2f(acc1[0]) * bc1[0];
                p11 = exp2f(acc1[1]) * bc1[1];
                p12 = exp2f(acc1[2]) * bc1[2];
                p13 = exp2f(acc1[3]) * bc1[3];
            } else {
                p00 = exp2f(acc0[0]);
                p01 = exp2f(acc0[1]);
                p02 = exp2f(acc0[2]);
                p03 = exp2f(acc0[3]);
                p10 = exp2f(acc1[0]);
                p11 = exp2f(acc1[1]);
                p12 = exp2f(acc1[2]);
                p13 = exp2f(acc1[3]);
            }
            dsum[qt] += ((p00 + p01) + (p02 + p03)) + ((p10 + p11) + (p12 + p13));

            pau[qt].u[0] = cvt_pk_bf16(p00, p01);
            pau[qt].u[1] = cvt_pk_bf16(p02, p03);
            pau[qt].u[2] = cvt_pk_bf16(p10, p11);
            pau[qt].u[3] = cvt_pk_bf16(p12, p13);
        }

#pragma unroll
        for (int ht = 0; ht < 4; ++ht) {
            const int h = ht * 16 + c;
            const int sw = (h & 7) << 4;
            const char* vr = vb + h * 128;
            union { s16x4 q[2]; short8 s; } vfu;
            vfu.q[0] = *(const s16x4*)(vr + ((wk * 64 + g * 8) ^ sw));
            vfu.q[1] = *(const s16x4*)(vr + ((wk * 64 + 32 + g * 8) ^ sw));
            vals[0][ht] = MFMA16(pau[0].s, vfu.s, vals[0][ht]);
            vals[1][ht] = MFMA16(pau[1].s, vfu.s, vals[1][ht]);
        }

        __syncthreads();
        { char* t0 = b0; b0 = b1; b1 = t0; }
        if (!NOBIAS) { bcur[0] = bn[0]; bcur[1] = bn[1]; bcur[2] = bn[2]; bcur[3] = bn[3]; }
    }

#pragma unroll
    for (int qt = 0; qt < 2; ++qt) {
        dsum[qt] += __shfl_xor(dsum[qt], 16);
        dsum[qt] += __shfl_xor(dsum[qt], 32);
    }

    float* rv = (float*)smem;
#pragma unroll
    for (int qt = 0; qt < 2; ++qt)
#pragma unroll
        for (int ht = 0; ht < 4; ++ht)
#pragma unroll
            for (int r = 0; r < 4; ++r)
                rv[(wk * 64 + wq * 32 + qt * 16 + g * 4 + r) * 65 + ht * 16 + c] = vals[qt][ht][r];
    if (g == 0) {
#pragma unroll
        for (int qt = 0; qt < 2; ++qt)
            rv[(wk * 64 + wq * 32 + qt * 16 + c) * 65 + 64] = dsum[qt];
    }
    __syncthreads();

    const int h = tid & 63;
    for (int qq = tid >> 6; qq < QB2; qq += 4) {
        const float v = rv[qq * 65 + h] + rv[(64 + qq) * 65 + h];
        __builtin_nontemporal_store(v, &pv[((size_t)bid * QB2 + qq) * H + h]);
        if (h == 0) {
            const float d = rv[qq * 65 + 64] + rv[(64 + qq) * 65 + 64];
            __builtin_nontemporal_store(d, &pd[(size_t)bid * QB2 + qq]);
        }
    }
}

// -------- kernel 3: combine key-split partials, divide, ELU --------
__global__ __launch_bounds__(256) void reduce_kernel(const float* __restrict__ pv,
                                                     const float* __restrict__ pd,
                                                     float* __restrict__ out) {
    const int i = blockIdx.x * 256 + threadIdx.x;
    const int q = i >> 6, h = i & 63;
    const int qc = q >> 6, qi = q & 63;
    float v = 0.f, d = 0.f;
#pragma unroll
    for (int ks = 0; ks < KSPLIT; ++ks) {
        const size_t row = (size_t)(qc * KSPLIT + ks) * QB2 + qi;
        v += __builtin_nontemporal_load(&pv[row * H + h]);
        d += __builtin_nontemporal_load(&pd[row]);
    }
    const float x = v / (d + 1e-19f);
    out[i] = x > 0.f ? x : expm1f(x);
}

extern "C" void kernel_launch(void* const* d_in, const int* in_sizes, int n_in,
                              void* d_out, int out_size, void* d_ws, size_t ws_size,
                              hipStream_t stream) {
    const float* seq  = (const float*)d_in[0];
    const float* bias = (const float*)d_in[1];
    const float* W1   = (const float*)d_in[2];
    const float* W2   = (const float*)d_in[3];
    float* out = (float*)d_out;

    const size_t NBLK = (N / QB2) * KSPLIT;        // 512
    unsigned short* Qb  = (unsigned short*)d_ws;   // 1 MB
    unsigned short* Kb  = Qb + (size_t)N * H;      // 1 MB
    unsigned short* QT  = Kb + (size_t)N * H;      // 1 MB
    unsigned short* W1T = QT + (size_t)N * H;      // 16 KB
    unsigned short* W2T = W1T + (size_t)H * FIN;   // 16 KB
    float* pv = (float*)(W2T + (size_t)H * FIN);   // 8 MB
    float* pd = pv + NBLK * QB2 * H;               // 128 KB
    float* pvX = pd + NBLK * QB2;                  // 8 MB (ablation scratch)
    float* pdX = pvX + NBLK * QB2 * H;             // 128 KB

    wprep_kernel<<<32, 256, 0, stream>>>(W1, W2, W1T, W2T);
    proj_kernel<<<N / 32, 256, 0, stream>>>(seq, W1T, W2T, Qb, Kb, QT);
    flash_kernel<0><<<NBLK, 256, 0, stream>>>(Qb, Kb, QT, bias, pv, pd);
    // diagnostic ablation: identical kernel minus the bias stream; output inert
    if (ws_size >= (size_t)24 << 20)
        flash_kernel<1><<<NBLK, 256, 0, stream>>>(Qb, Kb, QT, bias, pvX, pdX);
    reduce_kernel<<<(N * H) / 256, 256, 0, stream>>>(pv, pd, out);
}

// Round 14
// 73.631 us; speedup vs baseline: 1.8657x; 1.8657x over previous
//
#include <hip/hip_runtime.h>
#include <hip/hip_bf16.h>
#include <stdint.h>

#define N 8192
#define FIN 128
#define H 64
#define QB2 64                   // query rows per block (2x16 per wave)
#define MB2 64                   // keys per iteration
#define KSPLIT 4
#define KLEN (N / KSPLIT)        // 2048 keys per block
#define NIT3 (KLEN / MB2)        // 32 iterations
#define STAGE_BYTES 16384        // K 8KB + V^T 8KB

typedef __attribute__((ext_vector_type(4))) short s16x4;
typedef __attribute__((ext_vector_type(8))) short short8;
typedef __attribute__((ext_vector_type(4))) float f32x4;

#define MFMA16(a, b, c) __builtin_amdgcn_mfma_f32_16x16x32_bf16(a, b, c, 0, 0, 0)

typedef __attribute__((address_space(1))) const void* gas_p;
typedef __attribute__((address_space(3))) void* las_p;

static __device__ __forceinline__ void load_lds16(const void* g, void* l) {
    // dest is wave-uniform base; HW writes lane i at base + i*16.
    __builtin_amdgcn_global_load_lds((gas_p)g, (las_p)l, 16, 0, 0);
}

static __device__ __forceinline__ unsigned short f2bf(float f) {
    unsigned int u = __float_as_uint(f);
    unsigned int r = (u + 0x7FFFu + ((u >> 16) & 1u)) >> 16;
    return (unsigned short)r;
}

// pack two f32 -> two bf16 in one u32 (lo = a, hi = b)
static __device__ __forceinline__ unsigned int cvt_pk_bf16(float a, float b) {
    unsigned int r;
    asm("v_cvt_pk_bf16_f32 %0, %1, %2" : "=v"(r) : "v"(a), "v"(b));
    return r;
}

// -------- kernel 0: W -> W^T bf16; W2 pre-scaled by log2(e)/8 (K-side only) --------
__global__ __launch_bounds__(256) void wprep_kernel(const float* __restrict__ W1,
                                                    const float* __restrict__ W2,
                                                    unsigned short* __restrict__ W1T,
                                                    unsigned short* __restrict__ W2T) {
    const int i = blockIdx.x * 256 + threadIdx.x;
    const int h = i >> 7, f = i & 127;
    W1T[i] = f2bf(W1[f * H + h]);
    W2T[i] = f2bf(W2[f * H + h] * 0.18033688011112042f);  // log2(e)/8
}

// -------- kernel 1: MFMA projection + fused Q transpose --------
__global__ __launch_bounds__(256) void proj_kernel(const float* __restrict__ seq,
                                                   const unsigned short* __restrict__ W1T,
                                                   const unsigned short* __restrict__ W2T,
                                                   unsigned short* __restrict__ Qb,
                                                   unsigned short* __restrict__ Kb,
                                                   unsigned short* __restrict__ QT) {
    __shared__ unsigned short t2[64][40];
    const int tid = threadIdx.x;
    const int w = tid >> 6, lane = tid & 63;
    const int g = lane >> 4, c = lane & 15;
    const int wq = w & 1, ww = w >> 1;
    const int r0 = blockIdx.x * 32;
    const int rw = r0 + wq * 16;
    const unsigned short* WT = ww ? W2T : W1T;
    unsigned short* Ob = ww ? Kb : Qb;

    short8 af[4];
#pragma unroll
    for (int kc = 0; kc < 4; ++kc) {
        const float* sp = seq + (size_t)(rw + c) * FIN + kc * 32 + g * 8;
        const f32x4 s0 = *(const f32x4*)sp;
        const f32x4 s1 = *(const f32x4*)(sp + 4);
        short8 v;
#pragma unroll
        for (int j = 0; j < 4; ++j) {
            v[j] = (short)f2bf(s0[j]);
            v[4 + j] = (short)f2bf(s1[j]);
        }
        af[kc] = v;
    }

    f32x4 oa[4] = {};
#pragma unroll
    for (int kc = 0; kc < 4; ++kc) {
#pragma unroll
        for (int ht = 0; ht < 4; ++ht) {
            const short8 wf = *(const short8*)(WT + (size_t)(ht * 16 + c) * FIN + kc * 32 + g * 8);
            oa[ht] = MFMA16(af[kc], wf, oa[ht]);
        }
    }
#pragma unroll
    for (int ht = 0; ht < 4; ++ht)
#pragma unroll
        for (int r = 0; r < 4; ++r) {
            const unsigned short b = f2bf(oa[ht][r]);
            Ob[(size_t)(rw + g * 4 + r) * H + ht * 16 + c] = b;
            if (ww == 0) t2[ht * 16 + c][wq * 16 + g * 4 + r] = b;
        }
    __syncthreads();
    const int h = tid >> 2, part = tid & 3;
    const short8 v = *(const short8*)(&t2[h][part * 8]);
    *(short8*)(QT + (size_t)h * N + r0 + part * 8) = v;
}

// -------- kernel 2: flash partials — prefetch PINNED above compute --------
// Identical to the round-11 kernel (passing) except:
//  (1) sched_barrier(0) after the prefetch issue: the machine scheduler can
//      no longer sink the bias loads to just before __syncthreads, so the
//      268MB bias stream transfers UNDER the compute phase instead of
//      serially after it (round-12 ablation: 37us structure + 45us bias,
//      perfectly additive = zero overlap).
//  (2) bias loads are plain (not nontemporal) so L3 can absorb re-reads.
__global__ __launch_bounds__(256) void flash_kernel(const unsigned short* __restrict__ Qb,
                                                    const unsigned short* __restrict__ Kb,
                                                    const unsigned short* __restrict__ QT,
                                                    const float* __restrict__ bias,
                                                    float* __restrict__ pv,
                                                    float* __restrict__ pd) {
    __shared__ char smem[33280];  // stage 2x16KB; epilogue rv [2][64][65] f32 aliases

    const int tid = threadIdx.x;
    const int w = tid >> 6, lane = tid & 63;
    const int g = lane >> 4, c = lane & 15;
    const int wq = w >> 1, wk = w & 1;
    const int bid = blockIdx.x;
    const int q0 = (bid >> 2) * QB2;
    const int mbase = (bid & 3) * KLEN;

    // Q B-fragments for the wave's two 16-q tiles
    short8 qf[2][2];
#pragma unroll
    for (int qt = 0; qt < 2; ++qt) {
        const unsigned short* qrow = Qb + (size_t)(q0 + wq * 32 + qt * 16 + c) * H + g * 8;
        qf[qt][0] = *(const short8*)(qrow);
        qf[qt][1] = *(const short8*)(qrow + 32);
    }

    f32x4 vals[2][4] = {};   // [qt][ht]; D row=q(g*4+r), col=h(ht*16+c)
    float dsum[2] = {0.f, 0.f};

    // stage one 64-key tile (K 8KB + V^T 8KB); 4 global_load_lds per wave
    auto stage = [&](char* sbase, int m0) {
#pragma unroll
        for (int s2 = 0; s2 < 2; ++s2) {
            const int s = w * 2 + s2;          // 0..7
            {   // K: [64 m][64 h] bf16, swz byte ^= (m&7)<<4
                const int m = s * 8 + (lane >> 3);
                const int srcb = ((lane & 7) * 16) ^ ((m & 7) << 4);
                load_lds16((const char*)Kb + (size_t)(mbase + m0 + m) * 128 + srcb,
                           sbase + s * 1024);
            }
            {   // V^T: [64 h][64 m] bf16, swz byte ^= (h&7)<<4
                const int h = s * 8 + (lane >> 3);
                const int srcb = ((lane & 7) * 16) ^ ((h & 7) << 4);
                load_lds16((const char*)QT + (size_t)h * (N * 2) + (size_t)(mbase + m0) * 2 + srcb,
                           sbase + 8192 + s * 1024);
            }
        }
    };

    char* b0 = smem;
    char* b1 = smem + STAGE_BYTES;

    // bias row bases for the two q-tiles (lane reads row q, 4 keys per dwordx4)
    const float* bb0 = bias + (size_t)(q0 + wq * 32 + c) * N + mbase + wk * 32 + g * 4;
    const float* bb1 = bb0 + (size_t)16 * N;

    stage(b0, 0);
    f32x4 bcur[4];
    bcur[0] = *(const f32x4*)(bb0);      bcur[1] = *(const f32x4*)(bb0 + 16);
    bcur[2] = *(const f32x4*)(bb1);      bcur[3] = *(const f32x4*)(bb1 + 16);
    __syncthreads();

    for (int it = 0; it < NIT3; ++it) {
        f32x4 bn[4];
        bn[0] = bcur[0]; bn[1] = bcur[1]; bn[2] = bcur[2]; bn[3] = bcur[3];
        if (it + 1 < NIT3) {
            stage(b1, (it + 1) * MB2);
            const int o = (it + 1) * MB2;
            bn[0] = *(const f32x4*)(bb0 + o);      bn[1] = *(const f32x4*)(bb0 + o + 16);
            bn[2] = *(const f32x4*)(bb1 + o);      bn[3] = *(const f32x4*)(bb1 + o + 16);
        }
        // Pin the prefetch ABOVE the compute: nothing crosses this point.
        // Without it the scheduler sinks the bias loads to just before
        // __syncthreads (register-lifetime-optimal), serializing HBM.
        __builtin_amdgcn_sched_barrier(0);

        const char* kb = b0;
        const char* vb = b0 + 8192;

        // K A-fragments: A[row=key][k=h]; key = wk*32 + t*16 + c
        short8 kf[2][2];
#pragma unroll
        for (int t = 0; t < 2; ++t) {
            const int m = wk * 32 + t * 16 + c;
            const char* kr = kb + m * 128;
            const int sw = (m & 7) << 4;
            kf[t][0] = *(const short8*)(kr + ((g * 16) ^ sw));
            kf[t][1] = *(const short8*)(kr + ((64 + g * 16) ^ sw));
        }

        // ---- per q-tile: swapped QK^T, P in-register ----
        union { unsigned u[4]; short8 s; } pau[2];
#pragma unroll
        for (int qt = 0; qt < 2; ++qt) {
            f32x4 acc0 = {}, acc1 = {};
            acc0 = MFMA16(kf[0][0], qf[qt][0], acc0);
            acc0 = MFMA16(kf[0][1], qf[qt][1], acc0);
            acc1 = MFMA16(kf[1][0], qf[qt][0], acc1);
            acc1 = MFMA16(kf[1][1], qf[qt][1], acc1);

            const f32x4 bc0 = bcur[qt * 2];
            const f32x4 bc1 = bcur[qt * 2 + 1];
            const float p00 = exp2f(acc0[0]) * bc0[0];
            const float p01 = exp2f(acc0[1]) * bc0[1];
            const float p02 = exp2f(acc0[2]) * bc0[2];
            const float p03 = exp2f(acc0[3]) * bc0[3];
            const float p10 = exp2f(acc1[0]) * bc1[0];
            const float p11 = exp2f(acc1[1]) * bc1[1];
            const float p12 = exp2f(acc1[2]) * bc1[2];
            const float p13 = exp2f(acc1[3]) * bc1[3];
            dsum[qt] += ((p00 + p01) + (p02 + p03)) + ((p10 + p11) + (p12 + p13));

            pau[qt].u[0] = cvt_pk_bf16(p00, p01);
            pau[qt].u[1] = cvt_pk_bf16(p02, p03);
            pau[qt].u[2] = cvt_pk_bf16(p10, p11);
            pau[qt].u[3] = cvt_pk_bf16(p12, p13);
        }

        // ---- PV: V frags loaded once per ht, used by both q-tiles ----
#pragma unroll
        for (int ht = 0; ht < 4; ++ht) {
            const int h = ht * 16 + c;
            const int sw = (h & 7) << 4;
            const char* vr = vb + h * 128;
            union { s16x4 q[2]; short8 s; } vfu;
            vfu.q[0] = *(const s16x4*)(vr + ((wk * 64 + g * 8) ^ sw));       // keys 4g..4g+3
            vfu.q[1] = *(const s16x4*)(vr + ((wk * 64 + 32 + g * 8) ^ sw));  // keys 16+4g..+3
            vals[0][ht] = MFMA16(pau[0].s, vfu.s, vals[0][ht]);
            vals[1][ht] = MFMA16(pau[1].s, vfu.s, vals[1][ht]);
        }

        __syncthreads();  // stage(it+1)+bias(it+1) drained; buffer swap safe
        { char* t0 = b0; b0 = b1; b1 = t0; }
        bcur[0] = bn[0]; bcur[1] = bn[1]; bcur[2] = bn[2]; bcur[3] = bn[3];
    }

    // ---- denominator: sum the 4 g-lanes of each q-row ----
#pragma unroll
    for (int qt = 0; qt < 2; ++qt) {
        dsum[qt] += __shfl_xor(dsum[qt], 16);
        dsum[qt] += __shfl_xor(dsum[qt], 32);
    }

    // ---- cross-wk combine; rv [2 wk][64 q][65] aliases the stage buffers ----
    float* rv = (float*)smem;
#pragma unroll
    for (int qt = 0; qt < 2; ++qt)
#pragma unroll
        for (int ht = 0; ht < 4; ++ht)
#pragma unroll
            for (int r = 0; r < 4; ++r)
                rv[(wk * 64 + wq * 32 + qt * 16 + g * 4 + r) * 65 + ht * 16 + c] = vals[qt][ht][r];
    if (g == 0) {
#pragma unroll
        for (int qt = 0; qt < 2; ++qt)
            rv[(wk * 64 + wq * 32 + qt * 16 + c) * 65 + 64] = dsum[qt];
    }
    __syncthreads();

    const int h = tid & 63;
    for (int qq = tid >> 6; qq < QB2; qq += 4) {
        const float v = rv[qq * 65 + h] + rv[(64 + qq) * 65 + h];
        __builtin_nontemporal_store(v, &pv[((size_t)bid * QB2 + qq) * H + h]);
        if (h == 0) {
            const float d = rv[qq * 65 + 64] + rv[(64 + qq) * 65 + 64];
            __builtin_nontemporal_store(d, &pd[(size_t)bid * QB2 + qq]);
        }
    }
}

// -------- kernel 3: combine key-split partials, divide, ELU --------
__global__ __launch_bounds__(256) void reduce_kernel(const float* __restrict__ pv,
                                                     const float* __restrict__ pd,
                                                     float* __restrict__ out) {
    const int i = blockIdx.x * 256 + threadIdx.x;  // N*H
    const int q = i >> 6, h = i & 63;
    const int qc = q >> 6, qi = q & 63;
    float v = 0.f, d = 0.f;
#pragma unroll
    for (int ks = 0; ks < KSPLIT; ++ks) {
        const size_t row = (size_t)(qc * KSPLIT + ks) * QB2 + qi;
        v += __builtin_nontemporal_load(&pv[row * H + h]);
        d += __builtin_nontemporal_load(&pd[row]);
    }
    const float x = v / (d + 1e-19f);
    out[i] = x > 0.f ? x : expm1f(x);
}

extern "C" void kernel_launch(void* const* d_in, const int* in_sizes, int n_in,
                              void* d_out, int out_size, void* d_ws, size_t ws_size,
                              hipStream_t stream) {
    const float* seq  = (const float*)d_in[0];
    const float* bias = (const float*)d_in[1];
    const float* W1   = (const float*)d_in[2];
    const float* W2   = (const float*)d_in[3];
    float* out = (float*)d_out;

    const size_t NBLK = (N / QB2) * KSPLIT;        // 512
    unsigned short* Qb  = (unsigned short*)d_ws;   // 1 MB
    unsigned short* Kb  = Qb + (size_t)N * H;      // 1 MB
    unsigned short* QT  = Kb + (size_t)N * H;      // 1 MB
    unsigned short* W1T = QT + (size_t)N * H;      // 16 KB
    unsigned short* W2T = W1T + (size_t)H * FIN;   // 16 KB
    float* pv = (float*)(W2T + (size_t)H * FIN);   // 8 MB
    float* pd = pv + NBLK * QB2 * H;               // 128 KB

    wprep_kernel<<<32, 256, 0, stream>>>(W1, W2, W1T, W2T);
    proj_kernel<<<N / 32, 256, 0, stream>>>(seq, W1T, W2T, Qb, Kb, QT);
    flash_kernel<<<NBLK, 256, 0, stream>>>(Qb, Kb, QT, bias, pv, pd);
    reduce_kernel<<<(N * H) / 256, 256, 0, stream>>>(pv, pd, out);
}